// Round 3
// baseline (255.704 us; speedup 1.0000x reference)
//
#include <hip/hip_runtime.h>
#include <hip/hip_bf16.h>

// ---------------------------------------------------------------------------
// Attention_58248346469030:  out = softmax((x@Wq)(x@Wk)^T * sc) @ (x@Wv) @ Wout + b
// B=4, S=2048, DIM=1024, INNER=1024 (full-dim attention, no head split).
//
// Pipeline (fp16/bf16 MFMA, fp32 accumulate):
//   prep:  x -> fp16;  W_qkv -> fp16 transposed [n][k] (q pre-scaled by 0.125);
//          W_out -> fp16 transposed.
//   1) qkv  = x @ W_qkv       (q/k fp16 -> qkv buf; v bf16 -> VT transposed directly)
//   2) P    = exp(q @ k^T)    (fp16 MFMA, bf16 out, no max-subtract: |dots|<~25)
//   3) invl = 1 / rowsum(P)
//   4) attn = (P @ V) * invl  (bf16 MFMA, fp16 out)
//   5) out  = attn @ W_out + b
//
// GEMM core (all 4 GEMMs): 128x256 tile, BK=64, 512 thr (8 waves 2Mx4N,
// 64x64/wave), double-buffered LDS (96KB), T2 XOR-swizzle (via pre-swizzled
// global source for global_load_lds), T3/T4 phase-split w/ early prefetch
// issue + boundary-only vmcnt drain, T5 setprio around MFMA clusters.
// ---------------------------------------------------------------------------

typedef short    s16x8 __attribute__((ext_vector_type(8)));
typedef short    s16x4 __attribute__((ext_vector_type(4)));
typedef float    fx4   __attribute__((ext_vector_type(4)));
typedef _Float16 h16x8 __attribute__((ext_vector_type(8)));

__device__ __forceinline__ short f2bs(float f) {
  __hip_bfloat16 h = __float2bfloat16(f);
  short s; __builtin_memcpy(&s, &h, 2); return s;
}
__device__ __forceinline__ short f2hs(float f) {
  _Float16 h = (_Float16)f;
  short s; __builtin_memcpy(&s, &h, 2); return s;
}
__device__ __forceinline__ float b2f(short s) {
  unsigned u = ((unsigned)(unsigned short)s) << 16;
  float f; __builtin_memcpy(&f, &u, 4); return f;
}

__device__ __forceinline__ void gload16(const void* g, void* l) {
  __builtin_amdgcn_global_load_lds(
      (const __attribute__((address_space(1))) void*)g,
      (__attribute__((address_space(3))) void*)l, 16, 0, 0);
}

// ---------------- prep kernels ----------------

__global__ void cvt_f32_f16(const float* __restrict__ in, short* __restrict__ out, int n4) {
  int i = blockIdx.x * blockDim.x + threadIdx.x;
  if (i < n4) {
    float4 v = reinterpret_cast<const float4*>(in)[i];
    s16x4 o;
    o.x = f2hs(v.x); o.y = f2hs(v.y); o.z = f2hs(v.z); o.w = f2hs(v.w);
    reinterpret_cast<s16x4*>(out)[i] = o;
  }
}

__global__ void transpose_w(const float* __restrict__ W, int K, int N,
                            short* __restrict__ WT, float qscale, int scaleN) {
  __shared__ float tile[32][33];
  int k0 = blockIdx.y * 32, n0 = blockIdx.x * 32;
  int r = threadIdx.x >> 5, c = threadIdx.x & 31;
  for (int rr = r; rr < 32; rr += 8)
    tile[rr][c] = W[(size_t)(k0 + rr) * N + n0 + c];
  __syncthreads();
  for (int rr = r; rr < 32; rr += 8) {
    int n = n0 + rr;
    float s = (n < scaleN) ? qscale : 1.0f;
    WT[(size_t)n * K + k0 + c] = f2hs(tile[c][rr] * s);
  }
}

// invl[row] = 1 / sum_t P[row][t]
__global__ void row_sums(const short* __restrict__ P, float* __restrict__ invl) {
  int wid = threadIdx.x >> 6, lane = threadIdx.x & 63;
  int row = blockIdx.x * 4 + wid;
  const short* p = P + (size_t)row * 2048;
  float s = 0.f;
#pragma unroll
  for (int seg = 0; seg < 4; ++seg) {
    s16x8 v = *reinterpret_cast<const s16x8*>(p + seg * 512 + lane * 8);
#pragma unroll
    for (int j = 0; j < 8; ++j) s += b2f(v[j]);
  }
#pragma unroll
  for (int off = 32; off; off >>= 1) s += __shfl_xor(s, off);
  if (lane == 0) invl[row] = 1.0f / s;
}

// ---------------- 8-wave phase-split GEMM ----------------
// C[M][N] = A[M][K] @ B'[N][K]^T, 16-bit operands, k-contiguous rows.
// EPI: 0 = qkv write (q/k fp16 -> Cv; v bf16 -> Cv2=VT[b][d][t] transposed)
//      1 = exp -> bf16     2 = *aux[row] -> fp16     3 = +aux[col] -> fp32
template<int EPI, int DT>
__global__ __launch_bounds__(512, 2)
void gemm8(const short* __restrict__ A, int lda, long long bsA,
           const short* __restrict__ B, int ldb, long long bsB,
           void* __restrict__ Cv, int ldc, long long bsC,
           int K, const float* __restrict__ aux, long long bsAux,
           short* __restrict__ Cv2) {
  __shared__ __align__(16) short As[2][128 * 64];   // 2 x 16KB
  __shared__ __align__(16) short Bs[2][256 * 64];   // 2 x 32KB

  const int t = threadIdx.x;
  const int z = blockIdx.z;
  A += (size_t)z * bsA;
  B += (size_t)z * bsB;

  const int brow = blockIdx.y * 128;
  const int bcol = blockIdx.x * 256;

  const int lane = t & 63;
  const int wid  = t >> 6;
  const int wr = (wid >> 2) * 64;        // wave row offset (0 / 64)
  const int wc = (wid & 3) * 64;         // wave col offset (0/64/128/192)
  const int fr = lane & 15;
  const int fg = lane >> 4;

  // ---- staging geometry (T2 swizzle via pre-swizzled global source) ----
  // LDS element (row, col) holds global (row, col ^ ((row&7)<<3)).
  // Chunk ci = 8 rows x 64 cols (1KB); lane l -> LDS row ci*8+(l>>3),
  // col chunk (l&7); global src col = ((l&7)^(l>>3))*8.
  const int l8 = lane >> 3, l7 = lane & 7;
  const int scol = ((l7 ^ l8) * 8);
  // A: 16 chunks, wave stages {2*wid, 2*wid+1} (consumer-aligned).
  const short* Ag0 = A + (size_t)(brow + (wid * 2 + 0) * 8 + l8) * lda + scol;
  const short* Ag1 = A + (size_t)(brow + (wid * 2 + 1) * 8 + l8) * lda + scol;
  const int Ad0 = (wid * 2 + 0) * 512;
  const int Ad1 = (wid * 2 + 1) * 512;
  // B: 32 chunks; waves {0,1,4,5} stage cols 0-127, {2,3,6,7} cols 128-255.
  const int half = (wid & 2) >> 1;
  const int sub  = (wid & 1) | ((wid >> 2) << 1);
  const int cb0  = half * 16 + sub * 4;
  const short* Bg[4];
#pragma unroll
  for (int j = 0; j < 4; ++j)
    Bg[j] = B + (size_t)(bcol + (cb0 + j) * 8 + l8) * ldb + scol;

  // ---- frag-read swizzled column offsets ----
  const int f8  = (fr & 7) << 3;
  const int sc0 = (fg * 8) ^ f8;        // kk = 0
  const int sc1 = sc0 ^ 32;             // kk = 32

  fx4 acc[4][4] = {};
  const int NT = K >> 6;

  // prologue: stage tile 0 into buf 0
  {
    gload16(Ag0, &As[0][Ad0]);
    gload16(Ag1, &As[0][Ad1]);
#pragma unroll
    for (int j = 0; j < 4; ++j) gload16(Bg[j], &Bs[0][(cb0 + j) * 512]);
  }
  __syncthreads();                       // drains vmcnt+lgkm, publishes tile 0

  for (int tt = 0; tt < NT; ++tt) {
    const int p = tt & 1;
    const short* Ab = &As[p][0];
    const short* Bb = &Bs[p][0];

    // ---- phase 0: issue prefetch for tile tt+1, read A(all)+B(n=0,1) ----
    if (tt + 1 < NT) {
      const int ktn = (tt + 1) << 6;
      const int pn = (tt + 1) & 1;
      gload16(Ag0 + ktn, &As[pn][Ad0]);
      gload16(Ag1 + ktn, &As[pn][Ad1]);
#pragma unroll
      for (int j = 0; j < 4; ++j) gload16(Bg[j] + ktn, &Bs[pn][(cb0 + j) * 512]);
    }
    s16x8 a[4][2], b[4][2];
#pragma unroll
    for (int m = 0; m < 4; ++m) {
      const int ro = (wr + m * 16 + fr) * 64;
      a[m][0] = *reinterpret_cast<const s16x8*>(Ab + ro + sc0);
      a[m][1] = *reinterpret_cast<const s16x8*>(Ab + ro + sc1);
    }
#pragma unroll
    for (int n = 0; n < 2; ++n) {
      const int ro = (wc + n * 16 + fr) * 64;
      b[n][0] = *reinterpret_cast<const s16x8*>(Bb + ro + sc0);
      b[n][1] = *reinterpret_cast<const s16x8*>(Bb + ro + sc1);
    }
    __builtin_amdgcn_s_barrier();                     // raw: no vmcnt drain
    asm volatile("s_waitcnt lgkmcnt(0)" ::: "memory");
    __builtin_amdgcn_sched_barrier(0);
    __builtin_amdgcn_s_setprio(1);
#pragma unroll
    for (int m = 0; m < 4; ++m)
#pragma unroll
      for (int n = 0; n < 2; ++n)
#pragma unroll
        for (int kk = 0; kk < 2; ++kk) {
          if constexpr (DT == 0)
            acc[m][n] = __builtin_amdgcn_mfma_f32_16x16x32_f16(
                __builtin_bit_cast(h16x8, a[m][kk]), __builtin_bit_cast(h16x8, b[n][kk]),
                acc[m][n], 0, 0, 0);
          else
            acc[m][n] = __builtin_amdgcn_mfma_f32_16x16x32_bf16(a[m][kk], b[n][kk], acc[m][n], 0, 0, 0);
        }
    __builtin_amdgcn_s_setprio(0);

    // ---- phase 1: read B(n=2,3), MFMA second half ----
#pragma unroll
    for (int n = 2; n < 4; ++n) {
      const int ro = (wc + n * 16 + fr) * 64;
      b[n][0] = *reinterpret_cast<const s16x8*>(Bb + ro + sc0);
      b[n][1] = *reinterpret_cast<const s16x8*>(Bb + ro + sc1);
    }
    __builtin_amdgcn_s_barrier();                     // raw
    asm volatile("s_waitcnt lgkmcnt(0)" ::: "memory");
    __builtin_amdgcn_sched_barrier(0);
    __builtin_amdgcn_s_setprio(1);
#pragma unroll
    for (int m = 0; m < 4; ++m)
#pragma unroll
      for (int n = 2; n < 4; ++n)
#pragma unroll
        for (int kk = 0; kk < 2; ++kk) {
          if constexpr (DT == 0)
            acc[m][n] = __builtin_amdgcn_mfma_f32_16x16x32_f16(
                __builtin_bit_cast(h16x8, a[m][kk]), __builtin_bit_cast(h16x8, b[n][kk]),
                acc[m][n], 0, 0, 0);
          else
            acc[m][n] = __builtin_amdgcn_mfma_f32_16x16x32_bf16(a[m][kk], b[n][kk], acc[m][n], 0, 0, 0);
        }
    __builtin_amdgcn_s_setprio(0);

    // ---- tile boundary: drain own prefetch loads (old), publish buffer ----
    __syncthreads();   // emits s_waitcnt vmcnt(0) lgkmcnt(0); s_barrier
  }

  // ---- epilogue: D row = fg*4 + j, col = fr (per 16x16 frag) ----
  const int row0 = brow + wr + fg * 4;
  const int col0 = bcol + wc + fr;
  const float* auxp = aux + (size_t)z * bsAux;
  if constexpr (EPI == 3) {
    float* Cf = reinterpret_cast<float*>(Cv) + (size_t)z * bsC;
#pragma unroll
    for (int m = 0; m < 4; ++m)
#pragma unroll
      for (int n = 0; n < 4; ++n) {
        const int col = col0 + n * 16;
        const float bo = auxp[col];
#pragma unroll
        for (int j = 0; j < 4; ++j)
          Cf[(size_t)(row0 + m * 16 + j) * ldc + col] = acc[m][n][j] + bo;
      }
  } else if constexpr (EPI == 0) {
    short* Cb = reinterpret_cast<short*>(Cv);
    if (bcol < 2048) {                    // q/k columns -> fp16, row-major
#pragma unroll
      for (int m = 0; m < 4; ++m)
#pragma unroll
        for (int j = 0; j < 4; ++j) {
          const int row = row0 + m * 16 + j;
#pragma unroll
          for (int n = 0; n < 4; ++n)
            Cb[(size_t)row * ldc + col0 + n * 16] = f2hs(acc[m][n][j]);
        }
    } else {                              // v columns -> bf16 into VT[b][d][t]
#pragma unroll
      for (int m = 0; m < 4; ++m)
#pragma unroll
        for (int j = 0; j < 4; ++j) {
          const int row = row0 + m * 16 + j;
          const int zb = row >> 11, s = row & 2047;
#pragma unroll
          for (int n = 0; n < 4; ++n) {
            const int d = col0 + n * 16 - 2048;
            Cv2[((size_t)(zb << 10) + d) * 2048 + s] = f2bs(acc[m][n][j]);
          }
        }
    }
  } else {
    short* Cb = reinterpret_cast<short*>(Cv) + (size_t)z * bsC;
#pragma unroll
    for (int m = 0; m < 4; ++m)
#pragma unroll
      for (int j = 0; j < 4; ++j) {
        const int row = row0 + m * 16 + j;
        float rs = 1.0f;
        if constexpr (EPI == 2) rs = auxp[row];
#pragma unroll
        for (int n = 0; n < 4; ++n) {
          float v = acc[m][n][j];
          short o;
          if constexpr (EPI == 1) o = f2bs(exp2f(v * 1.4426950408889634f));
          else                    o = f2hs(v * rs);
          Cb[(size_t)row * ldc + col0 + n * 16] = o;
        }
      }
  }
}

// ---------------- launch ----------------

extern "C" void kernel_launch(void* const* d_in, const int* in_sizes, int n_in,
                              void* d_out, int out_size, void* d_ws, size_t ws_size,
                              hipStream_t stream) {
  const float* x    = (const float*)d_in[0];   // [4,2048,1024]
  const float* Wqkv = (const float*)d_in[1];   // [1024,3072]
  const float* Wout = (const float*)d_in[2];   // [1024,1024]
  const float* bout = (const float*)d_in[3];   // [1024]
  float* out = (float*)d_out;                  // [4,2048,1024] fp32

  char* ws = (char*)d_ws;
  short* qkv   = (short*)(ws + 0);             //  50331648  q/k fp16 [8192][3072]
  short* WqkvT = (short*)(ws + 50331648);      //   6291456  fp16 [3072][1024]
  short* WoutT = (short*)(ws + 56623104);      //   2097152  fp16 [1024][1024]
  short* P     = (short*)(ws + 58720256);      //  33554432  bf16 [4][2048][2048]
  short* VT    = (short*)(ws + 92274688);      //  16777216  bf16 [4][1024][2048]
  short* xh    = (short*)(ws + 109051904);     //  16777216  fp16 x (reused as attn)
  float* invl  = (float*)(ws + 125829120);     //     32768
  if (ws_size < 125861888) return;
  short* attn = xh;

  cvt_f32_f16<<<8192, 256, 0, stream>>>(x, xh, 8388608 / 4);
  transpose_w<<<dim3(96, 32), 256, 0, stream>>>(Wqkv, 1024, 3072, WqkvT, 0.125f, 1024);
  transpose_w<<<dim3(32, 32), 256, 0, stream>>>(Wout, 1024, 1024, WoutT, 1.0f, 0);

  // qkv = x @ W_qkv   (v written transposed into VT)
  gemm8<0, 0><<<dim3(12, 64, 1), 512, 0, stream>>>(
      xh, 1024, 0, WqkvT, 1024, 0, qkv, 3072, 0, 1024, bout, 0, VT);
  // P = exp(q @ k^T)
  gemm8<1, 0><<<dim3(8, 16, 4), 512, 0, stream>>>(
      qkv, 3072, 2048LL * 3072, qkv + 1024, 3072, 2048LL * 3072,
      P, 2048, 2048LL * 2048, 1024, bout, 0, nullptr);
  row_sums<<<2048, 256, 0, stream>>>(P, invl);
  // attn = (P @ V) * invl
  gemm8<2, 1><<<dim3(4, 16, 4), 512, 0, stream>>>(
      P, 2048, 2048LL * 2048, VT, 2048, 1024LL * 2048,
      attn, 1024, 2048LL * 1024, 2048, invl, 2048, nullptr);
  // out = attn @ W_out + b
  gemm8<3, 0><<<dim3(4, 64, 1), 512, 0, stream>>>(
      attn, 1024, 0, WoutT, 1024, 0, out, 1024, 0, 1024, bout, 0, nullptr);
}